// Round 7
// baseline (3256.648 us; speedup 1.0000x reference)
//
#include <hip/hip_runtime.h>

typedef unsigned short ushort_t;
typedef __attribute__((ext_vector_type(8))) short bf16x8;
typedef __attribute__((ext_vector_type(4))) float f32x4;
typedef __attribute__((ext_vector_type(4))) unsigned int u32x4;

#define BB 32
#define TT 64
#define HH 512
#define G4H 2048

__device__ __forceinline__ ushort_t f2bf(float f) {
    unsigned int u = __float_as_uint(f);
    unsigned int r = (u + 0x7fffu + ((u >> 16) & 1u)) >> 16;
    return (ushort_t)r;
}
__device__ __forceinline__ float sigf(float x) { return 1.f / (1.f + __expf(-x)); }
__device__ __forceinline__ float tanh_(float x) {
    float e = __expf(2.f * x);
    return 1.f - 2.f / (e + 1.f);
}
__device__ __forceinline__ float hsum4(f32x4 a) { return (a.x + a.y) + (a.z + a.w); }

// ---------------- zero init ----------------
__global__ void zero_init(float* zeros) {
    int t = threadIdx.x;
    if (t < 128) ((float4*)zeros)[t] = make_float4(0.f, 0.f, 0.f, 0.f); // 512 floats
}

// ---------------- embedding gather ----------------
__global__ void gather_rows(const int* __restrict__ idx, const float* __restrict__ emb,
                            float* __restrict__ out) {
    int row = blockIdx.x;      // 2048 rows
    int t = threadIdx.x;       // 64 threads
    int id = idx[row];
    float4 v = *(const float4*)(emb + (size_t)id * 256 + t * 4);
    *(float4*)(out + (size_t)row * 256 + t * 4) = v;
}

// ---------------- generic fp32 GEMM: C[M,N] = act(A[M,K] * B[N,K]^T + bias) ----------------
// mode 0: fp32 out, no act. mode 2: tanh then bf16 out.
__global__ __launch_bounds__(256) void gemm_f32(
    const float* __restrict__ A, int lda,
    const float* __restrict__ B, int ldb,
    const float* __restrict__ bias,
    void* __restrict__ Cv, int ldc,
    int M, int N, int K, int mode)
{
    __shared__ float As[16 * 68];
    __shared__ float Bs[16 * 68];
    const int tid = threadIdx.x;
    const int bm = blockIdx.y * 64, bn = blockIdx.x * 64;
    const int lr = tid >> 2, lk = (tid & 3) << 2;
    const int tr = (tid >> 4) << 2, tc = (tid & 15) << 2;
    float acc[4][4] = {};
    const int arow = bm + lr, brow = bn + lr;
    const bool aval = arow < M, bval = brow < N;
    const float* Ap = A + (size_t)arow * lda + lk;
    const float* Bp = B + (size_t)brow * ldb + lk;

    for (int k0 = 0; k0 < K; k0 += 16) {
        float4 av = make_float4(0.f, 0.f, 0.f, 0.f);
        float4 bv = make_float4(0.f, 0.f, 0.f, 0.f);
        if (aval) av = *(const float4*)(Ap + k0);
        if (bval) bv = *(const float4*)(Bp + k0);
        As[(lk + 0) * 68 + lr] = av.x; As[(lk + 1) * 68 + lr] = av.y;
        As[(lk + 2) * 68 + lr] = av.z; As[(lk + 3) * 68 + lr] = av.w;
        Bs[(lk + 0) * 68 + lr] = bv.x; Bs[(lk + 1) * 68 + lr] = bv.y;
        Bs[(lk + 2) * 68 + lr] = bv.z; Bs[(lk + 3) * 68 + lr] = bv.w;
        __syncthreads();
        #pragma unroll
        for (int kk = 0; kk < 16; kk++) {
            float4 a = *(const float4*)&As[kk * 68 + tr];
            float4 b = *(const float4*)&Bs[kk * 68 + tc];
            float ar[4] = {a.x, a.y, a.z, a.w};
            float br[4] = {b.x, b.y, b.z, b.w};
            #pragma unroll
            for (int i = 0; i < 4; i++)
                #pragma unroll
                for (int j = 0; j < 4; j++)
                    acc[i][j] = fmaf(ar[i], br[j], acc[i][j]);
        }
        __syncthreads();
    }
    #pragma unroll
    for (int i = 0; i < 4; i++) {
        int m = bm + tr + i;
        if (m >= M) continue;
        #pragma unroll
        for (int j = 0; j < 4; j++) {
            int n = bn + tc + j;
            if (n >= N) continue;
            float v = acc[i][j] + (bias ? bias[n] : 0.f);
            if (mode == 0) {
                ((float*)Cv)[(size_t)m * ldc + n] = v;
            } else {
                ((ushort_t*)Cv)[(size_t)m * ldc + n] = f2bf(tanh_(v));
            }
        }
    }
}

// ---------------- context mean ----------------
__global__ void mean_ctx(const float* __restrict__ e1, float* __restrict__ ctx) {
    int g = blockIdx.x * 256 + threadIdx.x; // 16384
    int b = g >> 9, u = g & 511;
    float s = 0.f;
    #pragma unroll 8
    for (int t = 0; t < TT; t++) s += e1[((size_t)b * TT + t) * HH + u];
    ctx[g] = s * (1.f / 64.f);
}

// ---- tagged poll: 32 slots (16 x dwordx4, sc0 sc1) + stage 32 floats to LDS ----
#define FOLD(q) { a &= q.x & q.y & q.z & q.w; o |= q.x | q.y | q.z | q.w; }
#define PUT(q, i) { dst[2*(i)]   = __uint_as_float((q.x << 16) | (q.y & 0xFFFFu)); \
                    dst[2*(i)+1] = __uint_as_float((q.z << 16) | (q.w & 0xFFFFu)); }
__device__ __forceinline__ void poll_stage32(const uint2* rp, unsigned int tag, float* dst) {
    u32x4 q0, q1, q2, q3, q4, q5, q6, q7, q8, q9, qa, qb, qc, qd, qe, qf;
    bool ok;
    do {
        asm volatile(
            "global_load_dwordx4 %0, %16, off sc0 sc1\n\t"
            "global_load_dwordx4 %1, %16, off offset:16 sc0 sc1\n\t"
            "global_load_dwordx4 %2, %16, off offset:32 sc0 sc1\n\t"
            "global_load_dwordx4 %3, %16, off offset:48 sc0 sc1\n\t"
            "global_load_dwordx4 %4, %16, off offset:64 sc0 sc1\n\t"
            "global_load_dwordx4 %5, %16, off offset:80 sc0 sc1\n\t"
            "global_load_dwordx4 %6, %16, off offset:96 sc0 sc1\n\t"
            "global_load_dwordx4 %7, %16, off offset:112 sc0 sc1\n\t"
            "global_load_dwordx4 %8, %16, off offset:128 sc0 sc1\n\t"
            "global_load_dwordx4 %9, %16, off offset:144 sc0 sc1\n\t"
            "global_load_dwordx4 %10, %16, off offset:160 sc0 sc1\n\t"
            "global_load_dwordx4 %11, %16, off offset:176 sc0 sc1\n\t"
            "global_load_dwordx4 %12, %16, off offset:192 sc0 sc1\n\t"
            "global_load_dwordx4 %13, %16, off offset:208 sc0 sc1\n\t"
            "global_load_dwordx4 %14, %16, off offset:224 sc0 sc1\n\t"
            "global_load_dwordx4 %15, %16, off offset:240 sc0 sc1\n\t"
            "s_waitcnt vmcnt(0)"
            : "=&v"(q0), "=&v"(q1), "=&v"(q2), "=&v"(q3),
              "=&v"(q4), "=&v"(q5), "=&v"(q6), "=&v"(q7),
              "=&v"(q8), "=&v"(q9), "=&v"(qa), "=&v"(qb),
              "=&v"(qc), "=&v"(qd), "=&v"(qe), "=&v"(qf)
            : "v"(rp) : "memory");
        unsigned int a = 0xFFFFFFFFu, o = 0u;
        FOLD(q0) FOLD(q1) FOLD(q2) FOLD(q3) FOLD(q4) FOLD(q5) FOLD(q6) FOLD(q7)
        FOLD(q8) FOLD(q9) FOLD(qa) FOLD(qb) FOLD(qc) FOLD(qd) FOLD(qe) FOLD(qf)
        ok = ((a >> 16) == tag) & ((o >> 16) == tag);
    } while (!ok);
    PUT(q0, 0)  PUT(q1, 1)  PUT(q2, 2)  PUT(q3, 3)
    PUT(q4, 4)  PUT(q5, 5)  PUT(q6, 6)  PUT(q7, 7)
    PUT(q8, 8)  PUT(q9, 9)  PUT(qa, 10) PUT(qb, 11)
    PUT(qc, 12) PUT(qd, 13) PUT(qe, 14) PUT(qf, 15)
}
#undef FOLD
#undef PUT

// ---------------- fused layer-pair LSTM scan (v7) ----------------
// 256 blocks: 0..127 = layer0 (v6-style scan), 128..255 = layer1 (consumes h0[t] from
// ring0 by tag; input projection Wih1·h0[t] computed on the fly, Wih1 streamed from L2).
// Per role: 2 batch-groups x 64 unit-blocks (8 units = 32 gate rows, 16 batches).
// Exchange: tagged (tag16|hi16, tag16|lo16) dwordx2 sc0 sc1 publishes; tag-polled
// dwordx4 sweeps. No barriers. 131 KB LDS forces 1 block/CU -> all 256 resident.
__global__ __launch_bounds__(256) void scan_pair(
    const float* __restrict__ gatesX0,  // [B*T][4H] layer0 x-proj incl bias
    const float* __restrict__ ctxAdd0,  // [B][4H] or null (decoder layer0)
    const float* __restrict__ Whh0,     // [4H][H]
    const float* __restrict__ Wih1,     // [4H][H] (streamed)
    const float* __restrict__ Whh1,     // [4H][H]
    const float* __restrict__ b1,       // [4H]
    const float* __restrict__ h0i0, int s_h0, const float* __restrict__ c0i0, int s_c0,
    const float* __restrict__ h0i1, int s_h1, const float* __restrict__ c0i1, int s_c1,
    float* __restrict__ out0,           // [B*T][H] layer0 h
    float* __restrict__ out1,           // [B*T][H] layer1 h
    float* __restrict__ cT0o, float* __restrict__ cT1o, // [B][H] or null
    uint2* __restrict__ ring0, uint2* __restrict__ ring1,
    int tb0, int tb1)
{
    __shared__ float wlds[32 * 516];    // own-layer Whh slice
    __shared__ float hA[16 * 516];      // L0: h0[t-1] ; L1: h0[t]
    __shared__ float hB[16 * 516];      // L1: h1[t-1] (unused by L0)
    __shared__ float glds[16 * 36];
    const int tid = threadIdx.x;
    const bool isL1 = blockIdx.x >= 128;
    const int rb = blockIdx.x & 127;
    const int bg = rb >> 6;             // batch group 0..1 (16 batches)
    const int ub = rb & 63;             // unit block
    const int u0 = ub * 8;
    // dot roles: thread = (batch bb, rows rr0 & rr0+16)
    const int bb = tid & 15;
    const int rr0 = tid >> 4;           // 0..15
    const int rr1 = rr0 + 16;
    const int grow0 = (rr0 >> 3) * HH + u0 + (rr0 & 7);
    const int grow1 = (rr1 >> 3) * HH + u0 + (rr1 & 7);
    const int batch = bg * 16 + bb;
    // staging roles
    const int srow = tid >> 4;          // batch row 0..15
    const int sc = tid & 15;            // 32-unit chunk

    { // stationary own-layer Whh -> LDS
        const float* W = isL1 ? Whh1 : Whh0;
        const int sr = tid >> 3, ch = (tid & 7) * 64;
        const float* wsrc = W + (size_t)((sr >> 3) * HH + u0 + (sr & 7)) * HH + ch;
        float* wdst = &wlds[sr * 516 + ch];
        #pragma unroll
        for (int j = 0; j < 64; j += 4) *(f32x4*)(wdst + j) = *(const f32x4*)(wsrc + j);
    }
    { // initial h: L0 -> hA (h0 init); L1 -> hB (h1 init)
        const float* hsrc = isL1 ? h0i1 : h0i0;
        const int hstr = isL1 ? s_h1 : s_h0;
        float* hd = (isL1 ? hB : hA) + srow * 516 + sc * 32;
        const float* hs = hsrc + (size_t)(bg * 16 + srow) * hstr + sc * 32;
        #pragma unroll
        for (int j = 0; j < 32; j += 4) *(f32x4*)(hd + j) = *(const f32x4*)(hs + j);
    }
    float creg = 0.f;
    if (tid < 128) {
        const int pb = tid >> 3, pu = tid & 7;
        const float* ci = isL1 ? c0i1 : c0i0;
        const int cs = isL1 ? s_c1 : s_c0;
        creg = ci[(size_t)(bg * 16 + pb) * cs + u0 + pu];
    }
    const float* gxp0 = gatesX0 + (size_t)batch * TT * G4H + grow0;
    const float* gxp1 = gatesX0 + (size_t)batch * TT * G4H + grow1;
    float xc0 = 0.f, xc1 = 0.f;
    if (!isL1 && ctxAdd0) {
        xc0 = ctxAdd0[(size_t)batch * G4H + grow0];
        xc1 = ctxAdd0[(size_t)batch * G4H + grow1];
    }
    float b1v0 = 0.f, b1v1 = 0.f;
    const float* wr0 = Wih1 + (size_t)grow0 * HH;
    const float* wr1 = Wih1 + (size_t)grow1 * HH;
    if (isL1) { b1v0 = b1[grow0]; b1v1 = b1[grow1]; }
    float* outp = isL1 ? out1 : out0;
    uint2* ringp = isL1 ? ring1 : ring0;
    float* cTp = isL1 ? cT1o : cT0o;
    const int tbase = isL1 ? tb1 : tb0;

    for (int t = 0; t < TT; ++t) {
        if (isL1) { // h0[t] from layer-0 ring
            const uint2* rp = ring0 + ((size_t)t * BB + bg * 16 + srow) * HH + sc * 32;
            poll_stage32(rp, (unsigned int)(tb0 + t + 1), &hA[srow * 516 + sc * 32]);
        }
        __syncthreads();
        float pre0, pre1;
        if (!isL1) {
            float g0 = gxp0[(size_t)t * G4H];
            float g1 = gxp1[(size_t)t * G4H];
            f32x4 a0 = {0.f, 0.f, 0.f, 0.f}, a1 = {0.f, 0.f, 0.f, 0.f};
            const float* hp = &hA[bb * 516];
            const float* w0 = &wlds[rr0 * 516];
            const float* w1 = &wlds[rr1 * 516];
            #pragma unroll 8
            for (int k = 0; k < HH; k += 4) {
                f32x4 hv = *(const f32x4*)(hp + k);
                f32x4 w0v = *(const f32x4*)(w0 + k);
                f32x4 w1v = *(const f32x4*)(w1 + k);
                a0.x = fmaf(hv.x, w0v.x, a0.x); a0.y = fmaf(hv.y, w0v.y, a0.y);
                a0.z = fmaf(hv.z, w0v.z, a0.z); a0.w = fmaf(hv.w, w0v.w, a0.w);
                a1.x = fmaf(hv.x, w1v.x, a1.x); a1.y = fmaf(hv.y, w1v.y, a1.y);
                a1.z = fmaf(hv.z, w1v.z, a1.z); a1.w = fmaf(hv.w, w1v.w, a1.w);
            }
            pre0 = g0 + xc0 + hsum4(a0);
            pre1 = g1 + xc1 + hsum4(a1);
        } else {
            f32x4 a0 = {0.f, 0.f, 0.f, 0.f}, a1 = {0.f, 0.f, 0.f, 0.f};
            const float* hp = &hA[bb * 516];
            const float* qp = &hB[bb * 516];
            const float* w0 = &wlds[rr0 * 516];
            const float* w1 = &wlds[rr1 * 516];
            #pragma unroll 4
            for (int k = 0; k < HH; k += 4) {
                f32x4 h0v = *(const f32x4*)(hp + k);
                f32x4 h1v = *(const f32x4*)(qp + k);
                f32x4 w0v = *(const f32x4*)(w0 + k);
                f32x4 w1v = *(const f32x4*)(w1 + k);
                f32x4 i0v = *(const f32x4*)(wr0 + k);
                f32x4 i1v = *(const f32x4*)(wr1 + k);
                a0.x = fmaf(i0v.x, h0v.x, fmaf(w0v.x, h1v.x, a0.x));
                a0.y = fmaf(i0v.y, h0v.y, fmaf(w0v.y, h1v.y, a0.y));
                a0.z = fmaf(i0v.z, h0v.z, fmaf(w0v.z, h1v.z, a0.z));
                a0.w = fmaf(i0v.w, h0v.w, fmaf(w0v.w, h1v.w, a0.w));
                a1.x = fmaf(i1v.x, h0v.x, fmaf(w1v.x, h1v.x, a1.x));
                a1.y = fmaf(i1v.y, h0v.y, fmaf(w1v.y, h1v.y, a1.y));
                a1.z = fmaf(i1v.z, h0v.z, fmaf(w1v.z, h1v.z, a1.z));
                a1.w = fmaf(i1v.w, h0v.w, fmaf(w1v.w, h1v.w, a1.w));
            }
            pre0 = b1v0 + hsum4(a0);
            pre1 = b1v1 + hsum4(a1);
        }
        glds[bb * 36 + rr0] = pre0;
        glds[bb * 36 + rr1] = pre1;
        __syncthreads();
        if (tid < 128) {
            const int pb = tid >> 3, pu = tid & 7;
            const int gbatch = bg * 16 + pb;
            float gi = glds[pb * 36 + 0 + pu];
            float gf = glds[pb * 36 + 8 + pu];
            float gg = glds[pb * 36 + 16 + pu];
            float go = glds[pb * 36 + 24 + pu];
            float c = sigf(gf) * creg + sigf(gi) * tanh_(gg);
            float h = sigf(go) * tanh_(c);
            creg = c;
            outp[((size_t)gbatch * TT + t) * HH + u0 + pu] = h;
            unsigned int hu = __float_as_uint(h);
            unsigned int tg = (unsigned int)(tbase + t + 1);
            uint2 w; w.x = (tg << 16) | (hu >> 16); w.y = (tg << 16) | (hu & 0xFFFFu);
            uint2* pp = ringp + ((size_t)t * BB + gbatch) * HH + u0 + pu;
            asm volatile("global_store_dwordx2 %0, %1, off sc0 sc1"
                         :: "v"(pp), "v"(w) : "memory");
            if (cTp && t == TT - 1) cTp[(size_t)gbatch * HH + u0 + pu] = c;
        }
        if (t + 1 < TT) { // own-layer recurrence input for next step
            if (!isL1) {
                const uint2* rp = ring0 + ((size_t)t * BB + bg * 16 + srow) * HH + sc * 32;
                poll_stage32(rp, (unsigned int)(tb0 + t + 1), &hA[srow * 516 + sc * 32]);
            } else {
                const uint2* rp = ring1 + ((size_t)t * BB + bg * 16 + srow) * HH + sc * 32;
                poll_stage32(rp, (unsigned int)(tb1 + t + 1), &hB[srow * 516 + sc * 32]);
            }
        }
    }
}

// ---------------- final projection: bf16 MFMA GEMM, C = A*B^T + bias ----------------
__global__ __launch_bounds__(256) void gemm_bf16(
    const ushort_t* __restrict__ A,
    const float* __restrict__ B,
    const float* __restrict__ bias,
    float* __restrict__ C, int M, int N, int K)
{
    __shared__ ushort_t As[128 * 72];
    __shared__ ushort_t Bs[128 * 72];
    const int tid = threadIdx.x;
    const int bm = blockIdx.x * 128, bn = blockIdx.y * 128;
    const int lane = tid & 63, wave = tid >> 6;
    const int wm = (wave & 1) * 64, wn = (wave >> 1) * 64;
    const int lr = lane & 15, lk = (lane >> 4) * 8;
    const int srow = tid >> 3, sch = tid & 7;
    f32x4 acc[4][4] = {};

    for (int k0 = 0; k0 < K; k0 += 64) {
        #pragma unroll
        for (int rr = 0; rr < 4; rr++) {
            int row = srow + rr * 32;
            const ushort_t* as = A + (size_t)(bm + row) * K + k0 + sch * 8;
            *(int4*)&As[row * 72 + sch * 8] = *(const int4*)as;
            const float* bs = B + (size_t)(bn + row) * K + k0 + sch * 8;
            float4 f0 = *(const float4*)bs;
            float4 f1 = *(const float4*)(bs + 4);
            int4 pk;
            pk.x = (int)f2bf(f0.x) | ((int)f2bf(f0.y) << 16);
            pk.y = (int)f2bf(f0.z) | ((int)f2bf(f0.w) << 16);
            pk.z = (int)f2bf(f1.x) | ((int)f2bf(f1.y) << 16);
            pk.w = (int)f2bf(f1.z) | ((int)f2bf(f1.w) << 16);
            *(int4*)&Bs[row * 72 + sch * 8] = pk;
        }
        __syncthreads();
        #pragma unroll
        for (int k2 = 0; k2 < 64; k2 += 32) {
            bf16x8 a[4], bfr[4];
            #pragma unroll
            for (int i = 0; i < 4; i++)
                a[i] = *(const bf16x8*)&As[(wm + i * 16 + lr) * 72 + k2 + lk];
            #pragma unroll
            for (int j = 0; j < 4; j++)
                bfr[j] = *(const bf16x8*)&Bs[(wn + j * 16 + lr) * 72 + k2 + lk];
            #pragma unroll
            for (int i = 0; i < 4; i++)
                #pragma unroll
                for (int j = 0; j < 4; j++)
                    acc[i][j] = __builtin_amdgcn_mfma_f32_16x16x32_bf16(a[i], bfr[j], acc[i][j], 0, 0, 0);
        }
        __syncthreads();
    }
    const int r0 = (lane >> 4) * 4;
    #pragma unroll
    for (int j = 0; j < 4; j++) {
        int col = bn + wn + j * 16 + lr;
        float bv = bias[col];
        #pragma unroll
        for (int i = 0; i < 4; i++) {
            int row = bm + wm + i * 16 + r0;
            #pragma unroll
            for (int q = 0; q < 4; q++)
                C[(size_t)(row + q) * N + col] = acc[i][j][q] + bv;
        }
    }
}

extern "C" void kernel_launch(void* const* d_in, const int* in_sizes, int n_in,
                              void* d_out, int out_size, void* d_ws, size_t ws_size,
                              hipStream_t stream) {
    const int*   src      = (const int*)d_in[0];
    const int*   tgt      = (const int*)d_in[1];
    const float* enc_emb  = (const float*)d_in[2];
    const float* dec_emb  = (const float*)d_in[3];
    const float* eWih0    = (const float*)d_in[4];
    const float* eWhh0    = (const float*)d_in[5];
    const float* eb0      = (const float*)d_in[6];
    const float* eWih1    = (const float*)d_in[7];
    const float* eWhh1    = (const float*)d_in[8];
    const float* eb1      = (const float*)d_in[9];
    const float* dWih0    = (const float*)d_in[10];
    const float* dWhh0    = (const float*)d_in[11];
    const float* db0      = (const float*)d_in[12];
    const float* dWih1    = (const float*)d_in[13];
    const float* dWhh1    = (const float*)d_in[14];
    const float* db1      = (const float*)d_in[15];
    const float* pW1      = (const float*)d_in[16];
    const float* pb1      = (const float*)d_in[17];
    const float* pW2      = (const float*)d_in[18];
    const float* pb2      = (const float*)d_in[19];
    float* out = (float*)d_out;

    // workspace carve (small persistent buffers)
    float* fws   = (float*)d_ws;
    float* zeros = fws;                        // 512 f (padded to 1024)
    float* cT0   = fws + 2048;                 // 16384 f
    float* cT1   = cT0 + 16384;
    float* ctx   = cT1 + 16384;
    float* ctxW  = ctx + 16384;                // 65536 f
    ushort_t* hid = (ushort_t*)(ctxW + 65536); // 2048*512 bf16

    // d_out scratch (all dead before final projection writes everything)
    float* G0  = out;                 // 2048*2048 gate buffers
    float* G1  = G0 + 4194304;        // (unused this round; layout kept)
    float* G2  = G1 + 4194304;
    float* G3  = G2 + 4194304;        // (unused)
    float* xe  = G3 + 4194304;        // 2048*256
    float* xd  = xe + 524288;
    float* e0  = xd + 524288;         // 2048*512
    float* e1  = e0 + 1048576;
    float* d0  = e1 + 1048576;
    float* d1v = d0 + 1048576;
    uint2* ring0 = (uint2*)(d1v + 1048576);  // [64][32][512] tagged h (8 MB)
    uint2* ring1 = ring0 + 1048576;          // [64][32][512] tagged h (8 MB)

    zero_init<<<1, 256, 0, stream>>>(zeros);
    gather_rows<<<2048, 64, 0, stream>>>(src, enc_emb, xe);
    gather_rows<<<2048, 64, 0, stream>>>(tgt, dec_emb, xd);

    // layer-0 input projections (K=256): encoder and decoder (xd part)
    gemm_f32<<<dim3(32, 32), 256, 0, stream>>>(xe, 256, eWih0, 256, eb0, G0, 2048, 2048, 2048, 256, 0);
    gemm_f32<<<dim3(32, 32), 256, 0, stream>>>(xd, 256, dWih0, 768, db0, G2, 2048, 2048, 2048, 256, 0);

    // fused encoder pair (layer0 + layer1 pipelined; layer1 x-proj on the fly)
    scan_pair<<<256, 256, 0, stream>>>(
        G0, nullptr, eWhh0, eWih1, eWhh1, eb1,
        zeros, 0, zeros, 0, zeros, 0, zeros, 0,
        e0, e1, cT0, cT1, ring0, ring1, 0, 64);

    // context
    mean_ctx<<<64, 256, 0, stream>>>(e1, ctx);
    gemm_f32<<<dim3(32, 1), 256, 0, stream>>>(ctx, 512, dWih0 + 256, 768, nullptr, ctxW, 2048, 32, 2048, 512, 0);

    // fused decoder pair
    scan_pair<<<256, 256, 0, stream>>>(
        G2, ctxW, dWhh0, dWih1, dWhh1, db1,
        e0 + 63 * 512, 64 * 512, cT0, 512,
        e1 + 63 * 512, 64 * 512, cT1, 512,
        d0, d1v, nullptr, nullptr, ring0, ring1, 128, 192);

    // projection: hid = tanh(d1*W1^T + b1) stored bf16; logits = hid*W2^T + b2 (MFMA)
    gemm_f32<<<dim3(8, 32), 256, 0, stream>>>(d1v, 512, pW1, 512, pb1, hid, 512, 2048, 512, 512, 2);
    gemm_bf16<<<dim3(16, 250), 256, 0, stream>>>(hid, pW2, pb2, out, 2048, 32000, 512);
}

// Round 8
// 1857.602 us; speedup vs baseline: 1.7531x; 1.7531x over previous
//
#include <hip/hip_runtime.h>

typedef unsigned short ushort_t;
typedef __attribute__((ext_vector_type(8))) short bf16x8;
typedef __attribute__((ext_vector_type(4))) float f32x4;
typedef __attribute__((ext_vector_type(4))) unsigned int u32x4;

#define BB 32
#define TT 64
#define HH 512
#define G4H 2048

__device__ __forceinline__ ushort_t f2bf(float f) {
    unsigned int u = __float_as_uint(f);
    unsigned int r = (u + 0x7fffu + ((u >> 16) & 1u)) >> 16;
    return (ushort_t)r;
}
__device__ __forceinline__ float sigf(float x) { return 1.f / (1.f + __expf(-x)); }
__device__ __forceinline__ float tanh_(float x) {
    float e = __expf(2.f * x);
    return 1.f - 2.f / (e + 1.f);
}

// ---------------- zero init (zeros vector for h0/c0) ----------------
__global__ void zero_init(float* zeros) {
    int t = threadIdx.x;
    if (t < 128) ((float4*)zeros)[t] = make_float4(0.f, 0.f, 0.f, 0.f); // 512 floats
}

// ---------------- embedding gather ----------------
__global__ void gather_rows(const int* __restrict__ idx, const float* __restrict__ emb,
                            float* __restrict__ out) {
    int row = blockIdx.x;      // 2048 rows
    int t = threadIdx.x;       // 64 threads
    int id = idx[row];
    float4 v = *(const float4*)(emb + (size_t)id * 256 + t * 4);
    *(float4*)(out + (size_t)row * 256 + t * 4) = v;
}

// ---------------- generic fp32 GEMM (kept for the tiny ctxW GEMM only) ----------------
__global__ __launch_bounds__(256) void gemm_f32(
    const float* __restrict__ A, int lda,
    const float* __restrict__ B, int ldb,
    const float* __restrict__ bias,
    void* __restrict__ Cv, int ldc,
    int M, int N, int K, int mode)
{
    __shared__ float As[16 * 68];
    __shared__ float Bs[16 * 68];
    const int tid = threadIdx.x;
    const int bm = blockIdx.y * 64, bn = blockIdx.x * 64;
    const int lr = tid >> 2, lk = (tid & 3) << 2;
    const int tr = (tid >> 4) << 2, tc = (tid & 15) << 2;
    float acc[4][4] = {};
    const int arow = bm + lr, brow = bn + lr;
    const bool aval = arow < M, bval = brow < N;
    const float* Ap = A + (size_t)arow * lda + lk;
    const float* Bp = B + (size_t)brow * ldb + lk;

    for (int k0 = 0; k0 < K; k0 += 16) {
        float4 av = make_float4(0.f, 0.f, 0.f, 0.f);
        float4 bv = make_float4(0.f, 0.f, 0.f, 0.f);
        if (aval) av = *(const float4*)(Ap + k0);
        if (bval) bv = *(const float4*)(Bp + k0);
        As[(lk + 0) * 68 + lr] = av.x; As[(lk + 1) * 68 + lr] = av.y;
        As[(lk + 2) * 68 + lr] = av.z; As[(lk + 3) * 68 + lr] = av.w;
        Bs[(lk + 0) * 68 + lr] = bv.x; Bs[(lk + 1) * 68 + lr] = bv.y;
        Bs[(lk + 2) * 68 + lr] = bv.z; Bs[(lk + 3) * 68 + lr] = bv.w;
        __syncthreads();
        #pragma unroll
        for (int kk = 0; kk < 16; kk++) {
            float4 a = *(const float4*)&As[kk * 68 + tr];
            float4 b = *(const float4*)&Bs[kk * 68 + tc];
            float ar[4] = {a.x, a.y, a.z, a.w};
            float br[4] = {b.x, b.y, b.z, b.w};
            #pragma unroll
            for (int i = 0; i < 4; i++)
                #pragma unroll
                for (int j = 0; j < 4; j++)
                    acc[i][j] = fmaf(ar[i], br[j], acc[i][j]);
        }
        __syncthreads();
    }
    #pragma unroll
    for (int i = 0; i < 4; i++) {
        int m = bm + tr + i;
        if (m >= M) continue;
        #pragma unroll
        for (int j = 0; j < 4; j++) {
            int n = bn + tc + j;
            if (n >= N) continue;
            float v = acc[i][j] + (bias ? bias[n] : 0.f);
            if (mode == 0) {
                ((float*)Cv)[(size_t)m * ldc + n] = v;
            } else {
                ((ushort_t*)Cv)[(size_t)m * ldc + n] = f2bf(tanh_(v));
            }
        }
    }
}

// ---------------- MFMA GEMM with f32->bf16 staging: C = act(A[M,K]*B[N,K]^T + bias) ----
// A,B fp32 (converted to bf16 during LDS staging). mode 0: f32 out. mode 2: tanh->bf16.
// Grid must tile M,N exactly (M%128==0, N%128==0).
__global__ __launch_bounds__(256) void gemm_mfma(
    const float* __restrict__ A, int lda,
    const float* __restrict__ B, int ldb,
    const float* __restrict__ bias,
    void* __restrict__ Cv, int ldc, int K, int mode)
{
    __shared__ ushort_t As[128 * 72];
    __shared__ ushort_t Bs[128 * 72];
    const int tid = threadIdx.x;
    const int bm = blockIdx.x * 128, bn = blockIdx.y * 128;
    const int lane = tid & 63, wave = tid >> 6;
    const int wm = (wave & 1) * 64, wn = (wave >> 1) * 64;
    const int lr = lane & 15, lk = (lane >> 4) * 8;
    const int srow = tid >> 3, sch = tid & 7;
    f32x4 acc[4][4] = {};

    for (int k0 = 0; k0 < K; k0 += 64) {
        #pragma unroll
        for (int rr = 0; rr < 4; rr++) {
            int row = srow + rr * 32;
            const float* as = A + (size_t)(bm + row) * lda + k0 + sch * 8;
            float4 a0 = *(const float4*)as;
            float4 a1 = *(const float4*)(as + 4);
            int4 pa;
            pa.x = (int)f2bf(a0.x) | ((int)f2bf(a0.y) << 16);
            pa.y = (int)f2bf(a0.z) | ((int)f2bf(a0.w) << 16);
            pa.z = (int)f2bf(a1.x) | ((int)f2bf(a1.y) << 16);
            pa.w = (int)f2bf(a1.z) | ((int)f2bf(a1.w) << 16);
            *(int4*)&As[row * 72 + sch * 8] = pa;
            const float* bs = B + (size_t)(bn + row) * ldb + k0 + sch * 8;
            float4 f0 = *(const float4*)bs;
            float4 f1 = *(const float4*)(bs + 4);
            int4 pk;
            pk.x = (int)f2bf(f0.x) | ((int)f2bf(f0.y) << 16);
            pk.y = (int)f2bf(f0.z) | ((int)f2bf(f0.w) << 16);
            pk.z = (int)f2bf(f1.x) | ((int)f2bf(f1.y) << 16);
            pk.w = (int)f2bf(f1.z) | ((int)f2bf(f1.w) << 16);
            *(int4*)&Bs[row * 72 + sch * 8] = pk;
        }
        __syncthreads();
        #pragma unroll
        for (int k2 = 0; k2 < 64; k2 += 32) {
            bf16x8 a[4], bfr[4];
            #pragma unroll
            for (int i = 0; i < 4; i++)
                a[i] = *(const bf16x8*)&As[(wm + i * 16 + lr) * 72 + k2 + lk];
            #pragma unroll
            for (int j = 0; j < 4; j++)
                bfr[j] = *(const bf16x8*)&Bs[(wn + j * 16 + lr) * 72 + k2 + lk];
            #pragma unroll
            for (int i = 0; i < 4; i++)
                #pragma unroll
                for (int j = 0; j < 4; j++)
                    acc[i][j] = __builtin_amdgcn_mfma_f32_16x16x32_bf16(a[i], bfr[j], acc[i][j], 0, 0, 0);
        }
        __syncthreads();
    }
    const int r0 = (lane >> 4) * 4;
    #pragma unroll
    for (int j = 0; j < 4; j++) {
        int col = bn + wn + j * 16 + lr;
        float bv = bias ? bias[col] : 0.f;
        #pragma unroll
        for (int i = 0; i < 4; i++) {
            int row = bm + wm + i * 16 + r0;
            #pragma unroll
            for (int q = 0; q < 4; q++) {
                float v = acc[i][j][q] + bv;
                if (mode == 0) ((float*)Cv)[(size_t)(row + q) * ldc + col] = v;
                else ((ushort_t*)Cv)[(size_t)(row + q) * ldc + col] = f2bf(tanh_(v));
            }
        }
    }
}

// ---------------- context mean ----------------
__global__ void mean_ctx(const float* __restrict__ e1, float* __restrict__ ctx) {
    int g = blockIdx.x * 256 + threadIdx.x; // 16384
    int b = g >> 9, u = g & 511;
    float s = 0.f;
    #pragma unroll 8
    for (int t = 0; t < TT; t++) s += e1[((size_t)b * TT + t) * HH + u];
    ctx[g] = s * (1.f / 64.f);
}

// ---------------- LSTM scan v6 (proven): tagged exchange on the plain VMEM path ------
// 256 blocks = 4 batch-groups (8 batches) x 64 unit-blocks (8 h-units = 32 gate rows).
// Producers publish h as TWO self-validating 4B words (tag16|hi16, tag16|lo16) with one
// global_store_dwordx2 sc0 sc1. Consumers poll 16 slots with one asm batch + waitcnt.
__global__ __launch_bounds__(256) void lstm_scan(
    const float* __restrict__ gatesX,  // [B*T][4H] precomputed x-projection (incl bias)
    const float* __restrict__ ctxAdd,  // [B][4H] or null (decoder layer0 context term)
    const float* __restrict__ Whh,     // [4H][H]
    const float* __restrict__ h0, int h0_stride,
    const float* __restrict__ c0, int c0_stride,
    float* __restrict__ out,           // [B*T][H] (plain stores; read by later kernels)
    float* __restrict__ cT,            // [B][H] or null
    uint2* __restrict__ ring,          // [T][B][H] tagged h exchange
    int tag_base)                      // layer*64; tag for step t = tag_base+t+1 (<=256)
{
    __shared__ float wlds[32 * 516];
    __shared__ float hlds[8 * 516];
    __shared__ float glds[8 * 33];
    __shared__ float clds[64];
    const int tid = threadIdx.x;
    const int bg = blockIdx.x >> 6;        // batch group 0..3
    const int ub = blockIdx.x & 63;        // unit block 0..63
    const int u0 = ub * 8;
    const int bb = (tid >> 3) & 7;         // batch within group (dot role)
    const int rr = (tid >> 6) * 8 + (tid & 7); // row 0..31 (gate = rr>>3 = wave id)
    const int grow = (rr >> 3) * HH + u0 + (rr & 7);
    const int bglob = bg * 8 + bb;

    { // stationary weights -> LDS: row = tid>>3, 64-col chunk = (tid&7)*64
        const int srow = tid >> 3, scol = (tid & 7) * 64;
        const int sg = srow >> 3, su = srow & 7;
        const float* wsrc = Whh + (size_t)(sg * HH + u0 + su) * HH + scol;
        float* wdst = &wlds[srow * 516 + scol];
        #pragma unroll
        for (int j = 0; j < 64; j += 4) *(f32x4*)(wdst + j) = *(const f32x4*)(wsrc + j);
    }
    if (tid < 64) { // c state: (bb2, uu2)
        clds[tid] = c0[(size_t)(bg * 8 + (tid >> 3)) * c0_stride + u0 + (tid & 7)];
    }
    const float xctx = ctxAdd ? ctxAdd[(size_t)bglob * G4H + grow] : 0.f;
    const int hrow = tid >> 5;             // staging role: batch row 0..7
    const int hc0 = tid & 31;              // lane within row
    const float* gxp = gatesX + (size_t)bglob * TT * G4H + grow;
    float gx_cur = gxp[0];
    float gx_nxt;

    { // stage h0 (plain loads) -> hlds
        const float* hs = h0 + (size_t)(bg * 8 + hrow) * h0_stride;
        float* hd = &hlds[hrow * 516 + hc0];
        #pragma unroll
        for (int j = 0; j < 16; j++) hd[32 * j] = hs[hc0 + 32 * j];
    }

    for (int t = 0; t < TT; t++) {
        __syncthreads();   // hlds (and prev glds consumption) ready
        {
            int tn = (t + 1 < TT) ? t + 1 : t;
            gx_nxt = gxp[(size_t)tn * G4H];
        }
        // dot(h_prev[bb,:], Whh[grow,:]) -- broadcast-friendly LDS reads
        f32x4 s = {0.f, 0.f, 0.f, 0.f};
        const float* hp = &hlds[bb * 516];
        const float* wp = &wlds[rr * 516];
        #pragma unroll 8
        for (int k = 0; k < HH; k += 4) {
            f32x4 hvv = *(const f32x4*)(hp + k);
            f32x4 wv = *(const f32x4*)(wp + k);
            s.x = fmaf(hvv.x, wv.x, s.x); s.y = fmaf(hvv.y, wv.y, s.y);
            s.z = fmaf(hvv.z, wv.z, s.z); s.w = fmaf(hvv.w, wv.w, s.w);
        }
        glds[bb * 33 + rr] = gx_cur + xctx + ((s.x + s.y) + (s.z + s.w));
        __syncthreads();   // glds ready; hlds free for restage
        const unsigned int tag = (unsigned int)(tag_base + t + 1);
        if (tid < 64) {
            const int bb2 = tid >> 3, uu2 = tid & 7;
            const int bg2 = bg * 8 + bb2;
            float gi = glds[bb2 * 33 + 0 + uu2];
            float gf = glds[bb2 * 33 + 8 + uu2];
            float gg = glds[bb2 * 33 + 16 + uu2];
            float go = glds[bb2 * 33 + 24 + uu2];
            float c = sigf(gf) * clds[tid] + sigf(gi) * tanh_(gg);
            float h = sigf(go) * tanh_(c);
            clds[tid] = c;
            out[((size_t)bg2 * TT + t) * HH + u0 + uu2] = h;  // plain (kernel-boundary readers)
            unsigned int hu = __float_as_uint(h);
            uint2 w;
            w.x = (tag << 16) | (hu >> 16);
            w.y = (tag << 16) | (hu & 0xFFFFu);
            uint2* pp = ring + ((size_t)t * BB + bg2) * HH + u0 + uu2;
            asm volatile("global_store_dwordx2 %0, %1, off sc0 sc1"
                         :: "v"(pp), "v"(w) : "memory");
            if (cT && t == TT - 1) cT[(size_t)bg2 * HH + u0 + uu2] = c;
        }
        if (t + 1 < TT) {
            // poll-stage h(t): 16 slots per thread, one batched sweep per retry
            const uint2* rp = ring + ((size_t)t * BB + bg * 8 + hrow) * HH + hc0;
            uint2 q0, q1, q2, q3, q4, q5, q6, q7, q8, q9, qa, qb, qc, qd, qe, qf;
            bool ok;
            do {
                asm volatile(
                    "global_load_dwordx2 %0, %16, off sc0 sc1\n\t"
                    "global_load_dwordx2 %1, %16, off offset:256 sc0 sc1\n\t"
                    "global_load_dwordx2 %2, %16, off offset:512 sc0 sc1\n\t"
                    "global_load_dwordx2 %3, %16, off offset:768 sc0 sc1\n\t"
                    "global_load_dwordx2 %4, %16, off offset:1024 sc0 sc1\n\t"
                    "global_load_dwordx2 %5, %16, off offset:1280 sc0 sc1\n\t"
                    "global_load_dwordx2 %6, %16, off offset:1536 sc0 sc1\n\t"
                    "global_load_dwordx2 %7, %16, off offset:1792 sc0 sc1\n\t"
                    "global_load_dwordx2 %8, %16, off offset:2048 sc0 sc1\n\t"
                    "global_load_dwordx2 %9, %16, off offset:2304 sc0 sc1\n\t"
                    "global_load_dwordx2 %10, %16, off offset:2560 sc0 sc1\n\t"
                    "global_load_dwordx2 %11, %16, off offset:2816 sc0 sc1\n\t"
                    "global_load_dwordx2 %12, %16, off offset:3072 sc0 sc1\n\t"
                    "global_load_dwordx2 %13, %16, off offset:3328 sc0 sc1\n\t"
                    "global_load_dwordx2 %14, %16, off offset:3584 sc0 sc1\n\t"
                    "global_load_dwordx2 %15, %16, off offset:3840 sc0 sc1\n\t"
                    "s_waitcnt vmcnt(0)"
                    : "=&v"(q0), "=&v"(q1), "=&v"(q2), "=&v"(q3),
                      "=&v"(q4), "=&v"(q5), "=&v"(q6), "=&v"(q7),
                      "=&v"(q8), "=&v"(q9), "=&v"(qa), "=&v"(qb),
                      "=&v"(qc), "=&v"(qd), "=&v"(qe), "=&v"(qf)
                    : "v"(rp) : "memory");
                unsigned int m0 = q0.x & q1.x & q2.x & q3.x & q4.x & q5.x & q6.x & q7.x
                                & q8.x & q9.x & qa.x & qb.x & qc.x & qd.x & qe.x & qf.x;
                unsigned int o0 = q0.x | q1.x | q2.x | q3.x | q4.x | q5.x | q6.x | q7.x
                                | q8.x | q9.x | qa.x | qb.x | qc.x | qd.x | qe.x | qf.x;
                unsigned int m1 = q0.y & q1.y & q2.y & q3.y & q4.y & q5.y & q6.y & q7.y
                                & q8.y & q9.y & qa.y & qb.y & qc.y & qd.y & qe.y & qf.y;
                unsigned int o1 = q0.y | q1.y | q2.y | q3.y | q4.y | q5.y | q6.y | q7.y
                                | q8.y | q9.y | qa.y | qb.y | qc.y | qd.y | qe.y | qf.y;
                ok = ((m0 >> 16) == tag) & ((o0 >> 16) == tag)
                   & ((m1 >> 16) == tag) & ((o1 >> 16) == tag);
            } while (!ok);
            float* hd = &hlds[hrow * 516 + hc0];
            hd[32 * 0]  = __uint_as_float((q0.x << 16) | (q0.y & 0xFFFFu));
            hd[32 * 1]  = __uint_as_float((q1.x << 16) | (q1.y & 0xFFFFu));
            hd[32 * 2]  = __uint_as_float((q2.x << 16) | (q2.y & 0xFFFFu));
            hd[32 * 3]  = __uint_as_float((q3.x << 16) | (q3.y & 0xFFFFu));
            hd[32 * 4]  = __uint_as_float((q4.x << 16) | (q4.y & 0xFFFFu));
            hd[32 * 5]  = __uint_as_float((q5.x << 16) | (q5.y & 0xFFFFu));
            hd[32 * 6]  = __uint_as_float((q6.x << 16) | (q6.y & 0xFFFFu));
            hd[32 * 7]  = __uint_as_float((q7.x << 16) | (q7.y & 0xFFFFu));
            hd[32 * 8]  = __uint_as_float((q8.x << 16) | (q8.y & 0xFFFFu));
            hd[32 * 9]  = __uint_as_float((q9.x << 16) | (q9.y & 0xFFFFu));
            hd[32 * 10] = __uint_as_float((qa.x << 16) | (qa.y & 0xFFFFu));
            hd[32 * 11] = __uint_as_float((qb.x << 16) | (qb.y & 0xFFFFu));
            hd[32 * 12] = __uint_as_float((qc.x << 16) | (qc.y & 0xFFFFu));
            hd[32 * 13] = __uint_as_float((qd.x << 16) | (qd.y & 0xFFFFu));
            hd[32 * 14] = __uint_as_float((qe.x << 16) | (qe.y & 0xFFFFu));
            hd[32 * 15] = __uint_as_float((qf.x << 16) | (qf.y & 0xFFFFu));
        }
        gx_cur = gx_nxt;
    }
}

// ---------------- final projection: bf16 MFMA GEMM, C = A*B^T + bias ----------------
// A: hid bf16 [M][K]. B: W2 fp32 [N][K] (converted to bf16 during staging). C fp32.
__global__ __launch_bounds__(256) void gemm_bf16(
    const ushort_t* __restrict__ A,
    const float* __restrict__ B,
    const float* __restrict__ bias,
    float* __restrict__ C, int M, int N, int K)
{
    __shared__ ushort_t As[128 * 72];
    __shared__ ushort_t Bs[128 * 72];
    const int tid = threadIdx.x;
    const int bm = blockIdx.x * 128, bn = blockIdx.y * 128;
    const int lane = tid & 63, wave = tid >> 6;
    const int wm = (wave & 1) * 64, wn = (wave >> 1) * 64;
    const int lr = lane & 15, lk = (lane >> 4) * 8;
    const int srow = tid >> 3, sch = tid & 7;
    f32x4 acc[4][4] = {};

    for (int k0 = 0; k0 < K; k0 += 64) {
        #pragma unroll
        for (int rr = 0; rr < 4; rr++) {
            int row = srow + rr * 32;
            const ushort_t* as = A + (size_t)(bm + row) * K + k0 + sch * 8;
            *(int4*)&As[row * 72 + sch * 8] = *(const int4*)as;
            const float* bs = B + (size_t)(bn + row) * K + k0 + sch * 8;
            float4 f0 = *(const float4*)bs;
            float4 f1 = *(const float4*)(bs + 4);
            int4 pk;
            pk.x = (int)f2bf(f0.x) | ((int)f2bf(f0.y) << 16);
            pk.y = (int)f2bf(f0.z) | ((int)f2bf(f0.w) << 16);
            pk.z = (int)f2bf(f1.x) | ((int)f2bf(f1.y) << 16);
            pk.w = (int)f2bf(f1.z) | ((int)f2bf(f1.w) << 16);
            *(int4*)&Bs[row * 72 + sch * 8] = pk;
        }
        __syncthreads();
        #pragma unroll
        for (int k2 = 0; k2 < 64; k2 += 32) {
            bf16x8 a[4], bfr[4];
            #pragma unroll
            for (int i = 0; i < 4; i++)
                a[i] = *(const bf16x8*)&As[(wm + i * 16 + lr) * 72 + k2 + lk];
            #pragma unroll
            for (int j = 0; j < 4; j++)
                bfr[j] = *(const bf16x8*)&Bs[(wn + j * 16 + lr) * 72 + k2 + lk];
            #pragma unroll
            for (int i = 0; i < 4; i++)
                #pragma unroll
                for (int j = 0; j < 4; j++)
                    acc[i][j] = __builtin_amdgcn_mfma_f32_16x16x32_bf16(a[i], bfr[j], acc[i][j], 0, 0, 0);
        }
        __syncthreads();
    }
    const int r0 = (lane >> 4) * 4;
    #pragma unroll
    for (int j = 0; j < 4; j++) {
        int col = bn + wn + j * 16 + lr;
        float bv = bias[col];
        #pragma unroll
        for (int i = 0; i < 4; i++) {
            int row = bm + wm + i * 16 + r0;
            #pragma unroll
            for (int q = 0; q < 4; q++)
                C[(size_t)(row + q) * N + col] = acc[i][j][q] + bv;
        }
    }
}

extern "C" void kernel_launch(void* const* d_in, const int* in_sizes, int n_in,
                              void* d_out, int out_size, void* d_ws, size_t ws_size,
                              hipStream_t stream) {
    const int*   src      = (const int*)d_in[0];
    const int*   tgt      = (const int*)d_in[1];
    const float* enc_emb  = (const float*)d_in[2];
    const float* dec_emb  = (const float*)d_in[3];
    const float* eWih0    = (const float*)d_in[4];
    const float* eWhh0    = (const float*)d_in[5];
    const float* eb0      = (const float*)d_in[6];
    const float* eWih1    = (const float*)d_in[7];
    const float* eWhh1    = (const float*)d_in[8];
    const float* eb1      = (const float*)d_in[9];
    const float* dWih0    = (const float*)d_in[10];
    const float* dWhh0    = (const float*)d_in[11];
    const float* db0      = (const float*)d_in[12];
    const float* dWih1    = (const float*)d_in[13];
    const float* dWhh1    = (const float*)d_in[14];
    const float* db1      = (const float*)d_in[15];
    const float* pW1      = (const float*)d_in[16];
    const float* pb1      = (const float*)d_in[17];
    const float* pW2      = (const float*)d_in[18];
    const float* pb2      = (const float*)d_in[19];
    float* out = (float*)d_out;

    // workspace carve (small persistent buffers)
    float* fws   = (float*)d_ws;
    float* zeros = fws;                        // 512 f (padded to 1024)
    float* cT0   = fws + 2048;                 // 16384 f
    float* cT1   = cT0 + 16384;
    float* ctx   = cT1 + 16384;
    float* ctxW  = ctx + 16384;                // 65536 f
    ushort_t* hid = (ushort_t*)(ctxW + 65536); // 2048*512 bf16

    // d_out scratch (all dead before final projection writes everything)
    float* G0  = out;                 // 2048*2048 gate buffers
    float* G1  = G0 + 4194304;
    float* G2  = G1 + 4194304;
    float* G3  = G2 + 4194304;
    float* xe  = G3 + 4194304;        // 2048*256
    float* xd  = xe + 524288;
    float* e0  = xd + 524288;         // 2048*512
    float* e1  = e0 + 1048576;
    float* d0  = e1 + 1048576;
    float* d1v = d0 + 1048576;
    uint2* ring = (uint2*)(d1v + 1048576); // [64][32][512] tagged h (8 MB)

    zero_init<<<1, 256, 0, stream>>>(zeros);
    gather_rows<<<2048, 64, 0, stream>>>(src, enc_emb, xe);
    gather_rows<<<2048, 64, 0, stream>>>(tgt, dec_emb, xd);

    // encoder layer 0 (MFMA x-projection, K=256)
    gemm_mfma<<<dim3(16, 16), 256, 0, stream>>>(xe, 256, eWih0, 256, eb0, G0, 2048, 256, 0);
    lstm_scan<<<256, 256, 0, stream>>>(G0, nullptr, eWhh0, zeros, 0, zeros, 0, e0, cT0, ring, 0);
    // encoder layer 1 (K=512)
    gemm_mfma<<<dim3(16, 16), 256, 0, stream>>>(e0, 512, eWih1, 512, eb1, G1, 2048, 512, 0);
    lstm_scan<<<256, 256, 0, stream>>>(G1, nullptr, eWhh1, zeros, 0, zeros, 0, e1, cT1, ring, 64);
    // context
    mean_ctx<<<64, 256, 0, stream>>>(e1, ctx);
    // decoder layer 0: gates = xd*Wih[:, :256]^T + b + ctx*Wih[:, 256:]^T (added in scan)
    gemm_mfma<<<dim3(16, 16), 256, 0, stream>>>(xd, 256, dWih0, 768, db0, G2, 2048, 256, 0);
    gemm_f32<<<dim3(32, 1), 256, 0, stream>>>(ctx, 512, dWih0 + 256, 768, nullptr, ctxW, 2048, 32, 2048, 512, 0);
    lstm_scan<<<256, 256, 0, stream>>>(G2, ctxW, dWhh0, e0 + 63 * 512, 64 * 512, cT0, 512, d0, nullptr, ring, 128);
    // decoder layer 1 (K=512)
    gemm_mfma<<<dim3(16, 16), 256, 0, stream>>>(d0, 512, dWih1, 512, db1, G3, 2048, 512, 0);
    lstm_scan<<<256, 256, 0, stream>>>(G3, nullptr, dWhh1, e1 + 63 * 512, 64 * 512, cT1, 512, d1v, nullptr, ring, 192);
    // projection: hid = tanh(d1*W1^T + b1) stored bf16 (MFMA); logits = hid*W2^T + b2 (MFMA)
    gemm_mfma<<<dim3(16, 4), 256, 0, stream>>>(d1v, 512, pW1, 512, pb1, hid, 512, 512, 2);
    gemm_bf16<<<dim3(16, 250), 256, 0, stream>>>(hid, pW2, pb2, out, 2048, 32000, 512);
}

// Round 9
// 1634.789 us; speedup vs baseline: 1.9921x; 1.1363x over previous
//
#include <hip/hip_runtime.h>

typedef unsigned short ushort_t;
typedef __attribute__((ext_vector_type(8))) short bf16x8;
typedef __attribute__((ext_vector_type(4))) float f32x4;

#define BB 32
#define TT 64
#define HH 512
#define G4H 2048

__device__ __forceinline__ ushort_t f2bf(float f) {
    unsigned int u = __float_as_uint(f);
    unsigned int r = (u + 0x7fffu + ((u >> 16) & 1u)) >> 16;
    return (ushort_t)r;
}
__device__ __forceinline__ float sigf(float x) { return 1.f / (1.f + __expf(-x)); }
__device__ __forceinline__ float tanh_(float x) {
    float e = __expf(2.f * x);
    return 1.f - 2.f / (e + 1.f);
}

// ---------------- zero init (zeros vector for h0/c0) ----------------
__global__ void zero_init(float* zeros) {
    int t = threadIdx.x;
    if (t < 128) ((float4*)zeros)[t] = make_float4(0.f, 0.f, 0.f, 0.f); // 512 floats
}

// ---------------- embedding gather ----------------
__global__ void gather_rows(const int* __restrict__ idx, const float* __restrict__ emb,
                            float* __restrict__ out) {
    int row = blockIdx.x;      // 2048 rows
    int t = threadIdx.x;       // 64 threads
    int id = idx[row];
    float4 v = *(const float4*)(emb + (size_t)id * 256 + t * 4);
    *(float4*)(out + (size_t)row * 256 + t * 4) = v;
}

// ---------------- generic fp32 GEMM (tiny ctxW GEMM only) ----------------
__global__ __launch_bounds__(256) void gemm_f32(
    const float* __restrict__ A, int lda,
    const float* __restrict__ B, int ldb,
    const float* __restrict__ bias,
    void* __restrict__ Cv, int ldc,
    int M, int N, int K, int mode)
{
    __shared__ float As[16 * 68];
    __shared__ float Bs[16 * 68];
    const int tid = threadIdx.x;
    const int bm = blockIdx.y * 64, bn = blockIdx.x * 64;
    const int lr = tid >> 2, lk = (tid & 3) << 2;
    const int tr = (tid >> 4) << 2, tc = (tid & 15) << 2;
    float acc[4][4] = {};
    const int arow = bm + lr, brow = bn + lr;
    const bool aval = arow < M, bval = brow < N;
    const float* Ap = A + (size_t)arow * lda + lk;
    const float* Bp = B + (size_t)brow * ldb + lk;

    for (int k0 = 0; k0 < K; k0 += 16) {
        float4 av = make_float4(0.f, 0.f, 0.f, 0.f);
        float4 bv = make_float4(0.f, 0.f, 0.f, 0.f);
        if (aval) av = *(const float4*)(Ap + k0);
        if (bval) bv = *(const float4*)(Bp + k0);
        As[(lk + 0) * 68 + lr] = av.x; As[(lk + 1) * 68 + lr] = av.y;
        As[(lk + 2) * 68 + lr] = av.z; As[(lk + 3) * 68 + lr] = av.w;
        Bs[(lk + 0) * 68 + lr] = bv.x; Bs[(lk + 1) * 68 + lr] = bv.y;
        Bs[(lk + 2) * 68 + lr] = bv.z; Bs[(lk + 3) * 68 + lr] = bv.w;
        __syncthreads();
        #pragma unroll
        for (int kk = 0; kk < 16; kk++) {
            float4 a = *(const float4*)&As[kk * 68 + tr];
            float4 b = *(const float4*)&Bs[kk * 68 + tc];
            float ar[4] = {a.x, a.y, a.z, a.w};
            float br[4] = {b.x, b.y, b.z, b.w};
            #pragma unroll
            for (int i = 0; i < 4; i++)
                #pragma unroll
                for (int j = 0; j < 4; j++)
                    acc[i][j] = fmaf(ar[i], br[j], acc[i][j]);
        }
        __syncthreads();
    }
    #pragma unroll
    for (int i = 0; i < 4; i++) {
        int m = bm + tr + i;
        if (m >= M) continue;
        #pragma unroll
        for (int j = 0; j < 4; j++) {
            int n = bn + tc + j;
            if (n >= N) continue;
            float v = acc[i][j] + (bias ? bias[n] : 0.f);
            if (mode == 0) ((float*)Cv)[(size_t)m * ldc + n] = v;
            else ((ushort_t*)Cv)[(size_t)m * ldc + n] = f2bf(tanh_(v));
        }
    }
}

// ---------------- MFMA GEMM with f32->bf16 staging ----------------
__global__ __launch_bounds__(256) void gemm_mfma(
    const float* __restrict__ A, int lda,
    const float* __restrict__ B, int ldb,
    const float* __restrict__ bias,
    void* __restrict__ Cv, int ldc, int K, int mode)
{
    __shared__ ushort_t As[128 * 72];
    __shared__ ushort_t Bs[128 * 72];
    const int tid = threadIdx.x;
    const int bm = blockIdx.x * 128, bn = blockIdx.y * 128;
    const int lane = tid & 63, wave = tid >> 6;
    const int wm = (wave & 1) * 64, wn = (wave >> 1) * 64;
    const int lr = lane & 15, lk = (lane >> 4) * 8;
    const int srow = tid >> 3, sch = tid & 7;
    f32x4 acc[4][4] = {};

    for (int k0 = 0; k0 < K; k0 += 64) {
        #pragma unroll
        for (int rr = 0; rr < 4; rr++) {
            int row = srow + rr * 32;
            const float* as = A + (size_t)(bm + row) * lda + k0 + sch * 8;
            float4 a0 = *(const float4*)as;
            float4 a1 = *(const float4*)(as + 4);
            int4 pa;
            pa.x = (int)f2bf(a0.x) | ((int)f2bf(a0.y) << 16);
            pa.y = (int)f2bf(a0.z) | ((int)f2bf(a0.w) << 16);
            pa.z = (int)f2bf(a1.x) | ((int)f2bf(a1.y) << 16);
            pa.w = (int)f2bf(a1.z) | ((int)f2bf(a1.w) << 16);
            *(int4*)&As[row * 72 + sch * 8] = pa;
            const float* bs = B + (size_t)(bn + row) * ldb + k0 + sch * 8;
            float4 f0 = *(const float4*)bs;
            float4 f1 = *(const float4*)(bs + 4);
            int4 pk;
            pk.x = (int)f2bf(f0.x) | ((int)f2bf(f0.y) << 16);
            pk.y = (int)f2bf(f0.z) | ((int)f2bf(f0.w) << 16);
            pk.z = (int)f2bf(f1.x) | ((int)f2bf(f1.y) << 16);
            pk.w = (int)f2bf(f1.z) | ((int)f2bf(f1.w) << 16);
            *(int4*)&Bs[row * 72 + sch * 8] = pk;
        }
        __syncthreads();
        #pragma unroll
        for (int k2 = 0; k2 < 64; k2 += 32) {
            bf16x8 a[4], bfr[4];
            #pragma unroll
            for (int i = 0; i < 4; i++)
                a[i] = *(const bf16x8*)&As[(wm + i * 16 + lr) * 72 + k2 + lk];
            #pragma unroll
            for (int j = 0; j < 4; j++)
                bfr[j] = *(const bf16x8*)&Bs[(wn + j * 16 + lr) * 72 + k2 + lk];
            #pragma unroll
            for (int i = 0; i < 4; i++)
                #pragma unroll
                for (int j = 0; j < 4; j++)
                    acc[i][j] = __builtin_amdgcn_mfma_f32_16x16x32_bf16(a[i], bfr[j], acc[i][j], 0, 0, 0);
        }
        __syncthreads();
    }
    const int r0 = (lane >> 4) * 4;
    #pragma unroll
    for (int j = 0; j < 4; j++) {
        int col = bn + wn + j * 16 + lr;
        float bv = bias ? bias[col] : 0.f;
        #pragma unroll
        for (int i = 0; i < 4; i++) {
            int row = bm + wm + i * 16 + r0;
            #pragma unroll
            for (int q = 0; q < 4; q++) {
                float v = acc[i][j][q] + bv;
                if (mode == 0) ((float*)Cv)[(size_t)(row + q) * ldc + col] = v;
                else ((ushort_t*)Cv)[(size_t)(row + q) * ldc + col] = f2bf(tanh_(v));
            }
        }
    }
}

// ---------------- context mean ----------------
__global__ void mean_ctx(const float* __restrict__ e1, float* __restrict__ ctx) {
    int g = blockIdx.x * 256 + threadIdx.x; // 16384
    int b = g >> 9, u = g & 511;
    float s = 0.f;
    #pragma unroll 8
    for (int t = 0; t < TT; t++) s += e1[((size_t)b * TT + t) * HH + u];
    ctx[g] = s * (1.f / 64.f);
}

// ---- tagged poll: 16 slots (dwordx2 sc0 sc1), stride-32 LDS staging (v6-verified) ----
#define POLL_ASM(rp)                                                       \
    asm volatile(                                                          \
        "global_load_dwordx2 %0, %16, off sc0 sc1\n\t"                     \
        "global_load_dwordx2 %1, %16, off offset:256 sc0 sc1\n\t"          \
        "global_load_dwordx2 %2, %16, off offset:512 sc0 sc1\n\t"          \
        "global_load_dwordx2 %3, %16, off offset:768 sc0 sc1\n\t"          \
        "global_load_dwordx2 %4, %16, off offset:1024 sc0 sc1\n\t"         \
        "global_load_dwordx2 %5, %16, off offset:1280 sc0 sc1\n\t"         \
        "global_load_dwordx2 %6, %16, off offset:1536 sc0 sc1\n\t"         \
        "global_load_dwordx2 %7, %16, off offset:1792 sc0 sc1\n\t"         \
        "global_load_dwordx2 %8, %16, off offset:2048 sc0 sc1\n\t"         \
        "global_load_dwordx2 %9, %16, off offset:2304 sc0 sc1\n\t"         \
        "global_load_dwordx2 %10, %16, off offset:2560 sc0 sc1\n\t"        \
        "global_load_dwordx2 %11, %16, off offset:2816 sc0 sc1\n\t"        \
        "global_load_dwordx2 %12, %16, off offset:3072 sc0 sc1\n\t"        \
        "global_load_dwordx2 %13, %16, off offset:3328 sc0 sc1\n\t"        \
        "global_load_dwordx2 %14, %16, off offset:3584 sc0 sc1\n\t"        \
        "global_load_dwordx2 %15, %16, off offset:3840 sc0 sc1\n\t"        \
        "s_waitcnt vmcnt(0)"                                               \
        : "=&v"(q0), "=&v"(q1), "=&v"(q2), "=&v"(q3),                      \
          "=&v"(q4), "=&v"(q5), "=&v"(q6), "=&v"(q7),                      \
          "=&v"(q8), "=&v"(q9), "=&v"(qa), "=&v"(qb),                      \
          "=&v"(qc), "=&v"(qd), "=&v"(qe), "=&v"(qf)                       \
        : "v"(rp) : "memory")
#define POLL_CHECK()                                                                        \
    unsigned int m0 = q0.x & q1.x & q2.x & q3.x & q4.x & q5.x & q6.x & q7.x                 \
                    & q8.x & q9.x & qa.x & qb.x & qc.x & qd.x & qe.x & qf.x;                \
    unsigned int o0 = q0.x | q1.x | q2.x | q3.x | q4.x | q5.x | q6.x | q7.x                 \
                    | q8.x | q9.x | qa.x | qb.x | qc.x | qd.x | qe.x | qf.x;                \
    unsigned int m1 = q0.y & q1.y & q2.y & q3.y & q4.y & q5.y & q6.y & q7.y                 \
                    & q8.y & q9.y & qa.y & qb.y & qc.y & qd.y & qe.y & qf.y;                \
    unsigned int o1 = q0.y | q1.y | q2.y | q3.y | q4.y | q5.y | q6.y | q7.y                 \
                    | q8.y | q9.y | qa.y | qb.y | qc.y | qd.y | qe.y | qf.y;                \
    ok = ((m0 >> 16) == tag) & ((o0 >> 16) == tag)                                          \
       & ((m1 >> 16) == tag) & ((o1 >> 16) == tag)

__device__ __forceinline__ void poll16_f32(const uint2* rp, unsigned int tag, float* hd) {
    uint2 q0, q1, q2, q3, q4, q5, q6, q7, q8, q9, qa, qb, qc, qd, qe, qf;
    bool ok;
    do { POLL_ASM(rp); POLL_CHECK(); } while (!ok);
    hd[32 * 0]  = __uint_as_float((q0.x << 16) | (q0.y & 0xFFFFu));
    hd[32 * 1]  = __uint_as_float((q1.x << 16) | (q1.y & 0xFFFFu));
    hd[32 * 2]  = __uint_as_float((q2.x << 16) | (q2.y & 0xFFFFu));
    hd[32 * 3]  = __uint_as_float((q3.x << 16) | (q3.y & 0xFFFFu));
    hd[32 * 4]  = __uint_as_float((q4.x << 16) | (q4.y & 0xFFFFu));
    hd[32 * 5]  = __uint_as_float((q5.x << 16) | (q5.y & 0xFFFFu));
    hd[32 * 6]  = __uint_as_float((q6.x << 16) | (q6.y & 0xFFFFu));
    hd[32 * 7]  = __uint_as_float((q7.x << 16) | (q7.y & 0xFFFFu));
    hd[32 * 8]  = __uint_as_float((q8.x << 16) | (q8.y & 0xFFFFu));
    hd[32 * 9]  = __uint_as_float((q9.x << 16) | (q9.y & 0xFFFFu));
    hd[32 * 10] = __uint_as_float((qa.x << 16) | (qa.y & 0xFFFFu));
    hd[32 * 11] = __uint_as_float((qb.x << 16) | (qb.y & 0xFFFFu));
    hd[32 * 12] = __uint_as_float((qc.x << 16) | (qc.y & 0xFFFFu));
    hd[32 * 13] = __uint_as_float((qd.x << 16) | (qd.y & 0xFFFFu));
    hd[32 * 14] = __uint_as_float((qe.x << 16) | (qe.y & 0xFFFFu));
    hd[32 * 15] = __uint_as_float((qf.x << 16) | (qf.y & 0xFFFFu));
}
__device__ __forceinline__ void poll16_bf16(const uint2* rp, unsigned int tag, ushort_t* hd) {
    uint2 q0, q1, q2, q3, q4, q5, q6, q7, q8, q9, qa, qb, qc, qd, qe, qf;
    bool ok;
    do { POLL_ASM(rp); POLL_CHECK(); } while (!ok);
    hd[32 * 0]  = f2bf(__uint_as_float((q0.x << 16) | (q0.y & 0xFFFFu)));
    hd[32 * 1]  = f2bf(__uint_as_float((q1.x << 16) | (q1.y & 0xFFFFu)));
    hd[32 * 2]  = f2bf(__uint_as_float((q2.x << 16) | (q2.y & 0xFFFFu)));
    hd[32 * 3]  = f2bf(__uint_as_float((q3.x << 16) | (q3.y & 0xFFFFu)));
    hd[32 * 4]  = f2bf(__uint_as_float((q4.x << 16) | (q4.y & 0xFFFFu)));
    hd[32 * 5]  = f2bf(__uint_as_float((q5.x << 16) | (q5.y & 0xFFFFu)));
    hd[32 * 6]  = f2bf(__uint_as_float((q6.x << 16) | (q6.y & 0xFFFFu)));
    hd[32 * 7]  = f2bf(__uint_as_float((q7.x << 16) | (q7.y & 0xFFFFu)));
    hd[32 * 8]  = f2bf(__uint_as_float((q8.x << 16) | (q8.y & 0xFFFFu)));
    hd[32 * 9]  = f2bf(__uint_as_float((q9.x << 16) | (q9.y & 0xFFFFu)));
    hd[32 * 10] = f2bf(__uint_as_float((qa.x << 16) | (qa.y & 0xFFFFu)));
    hd[32 * 11] = f2bf(__uint_as_float((qb.x << 16) | (qb.y & 0xFFFFu)));
    hd[32 * 12] = f2bf(__uint_as_float((qc.x << 16) | (qc.y & 0xFFFFu)));
    hd[32 * 13] = f2bf(__uint_as_float((qd.x << 16) | (qd.y & 0xFFFFu)));
    hd[32 * 14] = f2bf(__uint_as_float((qe.x << 16) | (qe.y & 0xFFFFu)));
    hd[32 * 15] = f2bf(__uint_as_float((qf.x << 16) | (qf.y & 0xFFFFu)));
}

// ---------------- fused layer-pair scan (v9) ----------------
// 256 blocks x 512 threads: blocks 0..127 = layer0 (v6-structure scan, 2 bgroups x 64
// ublocks, 16 batches/group, 8 units/block); blocks 128..255 = layer1 (same partition).
// L1's input projection Wih1·h0(t): register-stationary bf16 MFMA (r4-verified fragment
// layout), h0(t) staged bf16 in LDS [16][520] (M=16 = batch count, no padding).
// Recurrent dots fp32 VALU (v6). Exchange: v6 tagged dwordx2 sc0 sc1 rings.
// LDS ~126 KB -> exactly 1 block/CU -> all 256 co-resident; L0 never waits on L1.
__global__ __launch_bounds__(512) void scan_pair2(
    const float* __restrict__ gatesX0,  // [B*T][4H] layer0 x-proj incl bias
    const float* __restrict__ ctxAdd0,  // [B][4H] or null (decoder layer0)
    const float* __restrict__ Whh0,     // [4H][H]
    const float* __restrict__ Wih1,     // [4H][H] (-> register fragments, bf16)
    const float* __restrict__ Whh1,     // [4H][H]
    const float* __restrict__ b1,       // [4H]
    const float* __restrict__ h00, int sh00, const float* __restrict__ c00, int sc00,
    const float* __restrict__ h01, int sh01, const float* __restrict__ c01, int sc01,
    float* __restrict__ out0, float* __restrict__ out1,
    float* __restrict__ cT0o, float* __restrict__ cT1o,
    uint2* __restrict__ ring0, uint2* __restrict__ ring1,
    int tb0, int tb1)
{
    __shared__ float wlds[32 * 516];    // own-layer Whh slice (fp32)
    __shared__ float hmain[16 * 516];   // L0: h0(t-1); L1: h1(t-1)
    __shared__ float glds[16 * 36];     // h-dot results [batch][row]
    __shared__ ushort_t ah[16 * 520];   // L1: h0(t) bf16 (A-operand)
    __shared__ float pglds[8 * 256];    // L1: MFMA partials [kh*2+ni][batch*16+col]
    const int tid = threadIdx.x;
    const bool isL1 = blockIdx.x >= 128;
    const int rb = blockIdx.x & 127;
    const int bg = rb >> 6, ub = rb & 63, u0 = ub * 8;
    const int w = tid >> 6, l = tid & 63;
    const int bb = l >> 2, rr = w * 4 + (l & 3);       // dot role: batch 0..15, row 0..31
    const int grow = (rr >> 3) * HH + u0 + (rr & 7);
    const int batch = bg * 16 + bb;
    const int srow = tid >> 5, hc0 = tid & 31;         // staging role

    { // stationary own-layer Whh -> LDS
        const float* W = isL1 ? Whh1 : Whh0;
        const int sr = tid >> 4, ch = (tid & 15) * 32;
        const float* ws = W + (size_t)((sr >> 3) * HH + u0 + (sr & 7)) * HH + ch;
        float* wd = &wlds[sr * 516 + ch];
        #pragma unroll
        for (int j = 0; j < 32; j += 4) *(f32x4*)(wd + j) = *(const f32x4*)(ws + j);
    }
    // L1: stationary Wih1 bf16 B-fragments (r4-verified layout). Wave (ni,kh):
    // ni = n-tile (16 gate rows), kh = K-span of 128.
    const int ni = w & 1, kh = w >> 1, lr = l & 15, ls = l >> 4;
    bf16x8 bfrag[4];
    if (isL1) {
        const int nrow = ni * 16 + lr;
        const int gN = (nrow >> 3) * HH + u0 + (nrow & 7);
        const float* wr = Wih1 + (size_t)gN * HH + kh * 128 + ls * 8;
        #pragma unroll
        for (int kk = 0; kk < 4; kk++) {
            float f[8];
            *(f32x4*)&f[0] = *(const f32x4*)(wr + kk * 32);
            *(f32x4*)&f[4] = *(const f32x4*)(wr + kk * 32 + 4);
            bf16x8 hv;
            #pragma unroll
            for (int j = 0; j < 8; j++) hv[j] = (short)f2bf(f[j]);
            bfrag[kk] = hv;
        }
    }
    { // initial own-recurrence h -> hmain (plain loads)
        const float* hsrc = isL1 ? h01 : h00;
        const int hstr = isL1 ? sh01 : sh00;
        const float* hs = hsrc + (size_t)(bg * 16 + srow) * hstr;
        float* hd = &hmain[srow * 516 + hc0];
        #pragma unroll
        for (int j = 0; j < 16; j++) hd[32 * j] = hs[hc0 + 32 * j];
    }
    // pointwise-thread state
    const int pb = tid >> 3, pu = tid & 7, gbatch = bg * 16 + pb;
    float creg = 0.f, b1v0 = 0.f, b1v1 = 0.f, b1v2 = 0.f, b1v3 = 0.f;
    if (tid < 128) {
        const float* ci = isL1 ? c01 : c00;
        const int cs = isL1 ? sc01 : sc00;
        creg = ci[(size_t)gbatch * cs + u0 + pu];
        if (isL1) {
            b1v0 = b1[0 * HH + u0 + pu]; b1v1 = b1[1 * HH + u0 + pu];
            b1v2 = b1[2 * HH + u0 + pu]; b1v3 = b1[3 * HH + u0 + pu];
        }
    }
    float xctx = 0.f, gx_cur = 0.f, gx_nxt = 0.f;
    const float* gxp = nullptr;
    if (!isL1) {
        gxp = gatesX0 + (size_t)batch * TT * G4H + grow;
        gx_cur = gxp[0];
        if (ctxAdd0) xctx = ctxAdd0[(size_t)batch * G4H + grow];
    } else {
        // h0(0) from L0's first publish
        const uint2* rp = ring0 + ((size_t)0 * BB + bg * 16 + srow) * HH + hc0;
        poll16_bf16(rp, (unsigned int)(tb0 + 1), &ah[srow * 520 + hc0]);
    }
    float* outp = isL1 ? out1 : out0;
    uint2* ringp = isL1 ? ring1 : ring0;
    const int tbase = isL1 ? tb1 : tb0;

    for (int t = 0; t < TT; ++t) {
        __syncthreads();   // staged inputs ready; prev glds consumed
        if (!isL1) {
            int tn = (t + 1 < TT) ? t + 1 : t;
            gx_nxt = gxp[(size_t)tn * G4H];
            f32x4 s = {0.f, 0.f, 0.f, 0.f};
            const float* hp = &hmain[bb * 516];
            const float* wp = &wlds[rr * 516];
            #pragma unroll 8
            for (int k = 0; k < HH; k += 4) {
                f32x4 hv = *(const f32x4*)(hp + k);
                f32x4 wv = *(const f32x4*)(wp + k);
                s.x = fmaf(hv.x, wv.x, s.x); s.y = fmaf(hv.y, wv.y, s.y);
                s.z = fmaf(hv.z, wv.z, s.z); s.w = fmaf(hv.w, wv.w, s.w);
            }
            glds[bb * 36 + rr] = gx_cur + xctx + ((s.x + s.y) + (s.z + s.w));
        } else {
            // x-projection: 4 MFMA (wave's K-span 128), A = h0(t) bf16, B = Wih1 frags
            f32x4 acc = {0.f, 0.f, 0.f, 0.f};
            const ushort_t* ab = &ah[lr * 520 + kh * 128 + ls * 8];
            #pragma unroll
            for (int kk = 0; kk < 4; kk++) {
                bf16x8 av = *(const bf16x8*)(ab + kk * 32);
                acc = __builtin_amdgcn_mfma_f32_16x16x32_bf16(av, bfrag[kk], acc, 0, 0, 0);
            }
            #pragma unroll
            for (int q = 0; q < 4; q++)
                pglds[(kh * 2 + ni) * 256 + (ls * 4 + q) * 16 + lr] = acc[q];
            // recurrent h-dot (fp32)
            f32x4 s = {0.f, 0.f, 0.f, 0.f};
            const float* hp = &hmain[bb * 516];
            const float* wp = &wlds[rr * 516];
            #pragma unroll 8
            for (int k = 0; k < HH; k += 4) {
                f32x4 hv = *(const f32x4*)(hp + k);
                f32x4 wv = *(const f32x4*)(wp + k);
                s.x = fmaf(hv.x, wv.x, s.x); s.y = fmaf(hv.y, wv.y, s.y);
                s.z = fmaf(hv.z, wv.z, s.z); s.w = fmaf(hv.w, wv.w, s.w);
            }
            glds[bb * 36 + rr] = (s.x + s.y) + (s.z + s.w);
        }
        __syncthreads();
        const unsigned int tag = (unsigned int)(tbase + t + 1);
        if (tid < 128) {
            float pre[4];
            if (!isL1) {
                #pragma unroll
                for (int g = 0; g < 4; g++) pre[g] = glds[pb * 36 + g * 8 + pu];
            } else {
                float bv[4] = {b1v0, b1v1, b1v2, b1v3};
                #pragma unroll
                for (int g = 0; g < 4; g++) {
                    int r = g * 8 + pu;
                    int nit = r >> 4, cr = r & 15;
                    float p = glds[pb * 36 + r] + bv[g];
                    #pragma unroll
                    for (int k2 = 0; k2 < 4; k2++)
                        p += pglds[(k2 * 2 + nit) * 256 + pb * 16 + cr];
                    pre[g] = p;
                }
            }
            float c = sigf(pre[1]) * creg + sigf(pre[0]) * tanh_(pre[2]);
            float h = sigf(pre[3]) * tanh_(c);
            creg = c;
            outp[((size_t)gbatch * TT + t) * HH + u0 + pu] = h;
            unsigned int hu = __float_as_uint(h);
            uint2 wv2;
            wv2.x = (tag << 16) | (hu >> 16);
            wv2.y = (tag << 16) | (hu & 0xFFFFu);
            uint2* pp = ringp + ((size_t)t * BB + gbatch) * HH + u0 + pu;
            asm volatile("global_store_dwordx2 %0, %1, off sc0 sc1"
                         :: "v"(pp), "v"(wv2) : "memory");
            if (t == TT - 1) {
                if (!isL1 && cT0o) cT0o[(size_t)gbatch * HH + u0 + pu] = c;
                if (isL1 && cT1o)  cT1o[(size_t)gbatch * HH + u0 + pu] = c;
            }
        }
        if (t + 1 < TT) {
            if (!isL1) {
                const uint2* rp = ring0 + ((size_t)t * BB + bg * 16 + srow) * HH + hc0;
                poll16_f32(rp, tag, &hmain[srow * 516 + hc0]);
            } else {
                const uint2* rp1 = ring1 + ((size_t)t * BB + bg * 16 + srow) * HH + hc0;
                poll16_f32(rp1, tag, &hmain[srow * 516 + hc0]);
                const uint2* rp0 = ring0 + ((size_t)(t + 1) * BB + bg * 16 + srow) * HH + hc0;
                poll16_bf16(rp0, (unsigned int)(tb0 + t + 2), &ah[srow * 520 + hc0]);
            }
        }
        gx_cur = gx_nxt;
    }
}

// ---------------- final projection: bf16 MFMA GEMM, C = A*B^T + bias ----------------
__global__ __launch_bounds__(256) void gemm_bf16(
    const ushort_t* __restrict__ A,
    const float* __restrict__ B,
    const float* __restrict__ bias,
    float* __restrict__ C, int M, int N, int K)
{
    __shared__ ushort_t As[128 * 72];
    __shared__ ushort_t Bs[128 * 72];
    const int tid = threadIdx.x;
    const int bm = blockIdx.x * 128, bn = blockIdx.y * 128;
    const int lane = tid & 63, wave = tid >> 6;
    const int wm = (wave & 1) * 64, wn = (wave >> 1) * 64;
    const int lr = lane & 15, lk = (lane >> 4) * 8;
    const int srow = tid >> 3, sch = tid & 7;
    f32x4 acc[4][4] = {};

    for (int k0 = 0; k0 < K; k0 += 64) {
        #pragma unroll
        for (int rr = 0; rr < 4; rr++) {
            int row = srow + rr * 32;
            const ushort_t* as = A + (size_t)(bm + row) * K + k0 + sch * 8;
            *(int4*)&As[row * 72 + sch * 8] = *(const int4*)as;
            const float* bs = B + (size_t)(bn + row) * K + k0 + sch * 8;
            float4 f0 = *(const float4*)bs;
            float4 f1 = *(const float4*)(bs + 4);
            int4 pk;
            pk.x = (int)f2bf(f0.x) | ((int)f2bf(f0.y) << 16);
            pk.y = (int)f2bf(f0.z) | ((int)f2bf(f0.w) << 16);
            pk.z = (int)f2bf(f1.x) | ((int)f2bf(f1.y) << 16);
            pk.w = (int)f2bf(f1.z) | ((int)f2bf(f1.w) << 16);
            *(int4*)&Bs[row * 72 + sch * 8] = pk;
        }
        __syncthreads();
        #pragma unroll
        for (int k2 = 0; k2 < 64; k2 += 32) {
            bf16x8 a[4], bfr[4];
            #pragma unroll
            for (int i = 0; i < 4; i++)
                a[i] = *(const bf16x8*)&As[(wm + i * 16 + lr) * 72 + k2 + lk];
            #pragma unroll
            for (int j = 0; j < 4; j++)
                bfr[j] = *(const bf16x8*)&Bs[(wn + j * 16 + lr) * 72 + k2 + lk];
            #pragma unroll
            for (int i = 0; i < 4; i++)
                #pragma unroll
                for (int j = 0; j < 4; j++)
                    acc[i][j] = __builtin_amdgcn_mfma_f32_16x16x32_bf16(a[i], bfr[j], acc[i][j], 0, 0, 0);
        }
        __syncthreads();
    }
    const int r0 = (lane >> 4) * 4;
    #pragma unroll
    for (int j = 0; j < 4; j++) {
        int col = bn + wn + j * 16 + lr;
        float bv = bias[col];
        #pragma unroll
        for (int i = 0; i < 4; i++) {
            int row = bm + wm + i * 16 + r0;
            #pragma unroll
            for (int q = 0; q < 4; q++)
                C[(size_t)(row + q) * N + col] = acc[i][j][q] + bv;
        }
    }
}

extern "C" void kernel_launch(void* const* d_in, const int* in_sizes, int n_in,
                              void* d_out, int out_size, void* d_ws, size_t ws_size,
                              hipStream_t stream) {
    const int*   src      = (const int*)d_in[0];
    const int*   tgt      = (const int*)d_in[1];
    const float* enc_emb  = (const float*)d_in[2];
    const float* dec_emb  = (const float*)d_in[3];
    const float* eWih0    = (const float*)d_in[4];
    const float* eWhh0    = (const float*)d_in[5];
    const float* eb0      = (const float*)d_in[6];
    const float* eWih1    = (const float*)d_in[7];
    const float* eWhh1    = (const float*)d_in[8];
    const float* eb1      = (const float*)d_in[9];
    const float* dWih0    = (const float*)d_in[10];
    const float* dWhh0    = (const float*)d_in[11];
    const float* db0      = (const float*)d_in[12];
    const float* dWih1    = (const float*)d_in[13];
    const float* dWhh1    = (const float*)d_in[14];
    const float* db1      = (const float*)d_in[15];
    const float* pW1      = (const float*)d_in[16];
    const float* pb1      = (const float*)d_in[17];
    const float* pW2      = (const float*)d_in[18];
    const float* pb2      = (const float*)d_in[19];
    float* out = (float*)d_out;

    // workspace carve (small persistent buffers)
    float* fws   = (float*)d_ws;
    float* zeros = fws;                        // 512 f (padded to 1024)
    float* cT0   = fws + 2048;                 // 16384 f
    float* cT1   = cT0 + 16384;
    float* ctx   = cT1 + 16384;
    float* ctxW  = ctx + 16384;                // 65536 f
    ushort_t* hid = (ushort_t*)(ctxW + 65536); // 2048*512 bf16

    // d_out scratch (all dead before final projection writes everything)
    float* G0  = out;                 // 2048*2048 gate buffers
    float* G1  = G0 + 4194304;        // (unused; layout kept)
    float* G2  = G1 + 4194304;
    float* G3  = G2 + 4194304;        // (unused)
    float* xe  = G3 + 4194304;        // 2048*256
    float* xd  = xe + 524288;
    float* e0  = xd + 524288;         // 2048*512
    float* e1  = e0 + 1048576;
    float* d0  = e1 + 1048576;
    float* d1v = d0 + 1048576;
    uint2* ring0 = (uint2*)(d1v + 1048576);  // [64][32][512] tagged h (8 MB)
    uint2* ring1 = ring0 + 1048576;          // [64][32][512] tagged h (8 MB)

    zero_init<<<1, 256, 0, stream>>>(zeros);
    gather_rows<<<2048, 64, 0, stream>>>(src, enc_emb, xe);
    gather_rows<<<2048, 64, 0, stream>>>(tgt, dec_emb, xd);

    // layer-0 input projections (K=256, MFMA)
    gemm_mfma<<<dim3(16, 16), 256, 0, stream>>>(xe, 256, eWih0, 256, eb0, G0, 2048, 256, 0);
    gemm_mfma<<<dim3(16, 16), 256, 0, stream>>>(xd, 256, dWih0, 768, db0, G2, 2048, 256, 0);

    // fused encoder pair (enc0 + enc1 pipelined, skew 1)
    scan_pair2<<<256, 512, 0, stream>>>(
        G0, nullptr, eWhh0, eWih1, eWhh1, eb1,
        zeros, 0, zeros, 0, zeros, 0, zeros, 0,
        e0, e1, cT0, cT1, ring0, ring1, 0, 64);

    // context
    mean_ctx<<<64, 256, 0, stream>>>(e1, ctx);
    gemm_f32<<<dim3(32, 1), 256, 0, stream>>>(ctx, 512, dWih0 + 256, 768, nullptr, ctxW, 2048, 32, 2048, 512, 0);

    // fused decoder pair
    scan_pair2<<<256, 512, 0, stream>>>(
        G2, ctxW, dWhh0, dWih1, dWhh1, db1,
        e0 + 63 * 512, 64 * 512, cT0, 512,
        e1 + 63 * 512, 64 * 512, cT1, 512,
        d0, d1v, nullptr, nullptr, ring0, ring1, 128, 192);

    // projection: hid = tanh(d1*W1^T + b1) (MFMA, bf16 out); logits = hid*W2^T + b2
    gemm_mfma<<<dim3(16, 4), 256, 0, stream>>>(d1v, 512, pW1, 512, pb1, hid, 512, 512, 2);
    gemm_bf16<<<dim3(16, 250), 256, 0, stream>>>(hid, pW2, pb2, out, 2048, 32000, 512);
}